// Round 5
// baseline (111.187 us; speedup 1.0000x reference)
//
#include <hip/hip_runtime.h>

// B=65536 rows, C=512. ALL device buffers are FLOAT32 (per reference dtypes;
// confirmed behaviorally: bf16-read of inputs -> NaN (r1), bf16-write of
// output -> absmax 5.78 (r4), npz sizes match f32 both sides).
//   g_f [B,C], v_f [B,C], W [2,2C], b [2]  ->  out [B,2C] f32.
// out = [a0*g | a1*v], att = softmax([g|v] @ W^T + b, axis=1).
// Traffic: 268 MB read + 268 MB write = 536 MB -> ~85 us floor @ 6.3 TB/s.

__device__ __forceinline__ void load8f(const float* p, float* f) {
    float4 a = *reinterpret_cast<const float4*>(p);
    float4 b = *reinterpret_cast<const float4*>(p + 4);
    f[0] = a.x; f[1] = a.y; f[2] = a.z; f[3] = a.w;
    f[4] = b.x; f[5] = b.y; f[6] = b.z; f[7] = b.w;
}

__device__ __forceinline__ void store8f(float* p, const float* f) {
    float4 a, b;
    a.x = f[0]; a.y = f[1]; a.z = f[2]; a.w = f[3];
    b.x = f[4]; b.y = f[5]; b.z = f[6]; b.w = f[7];
    *reinterpret_cast<float4*>(p)     = a;
    *reinterpret_cast<float4*>(p + 4) = b;
}

__global__ __launch_bounds__(256) void attentive_fusion_kernel(
    const float* __restrict__ g, const float* __restrict__ v,
    const float* __restrict__ W, const float* __restrict__ b,
    float* __restrict__ out, int nrows)
{
    const int lane   = threadIdx.x & 63;
    const int wid    = (blockIdx.x * blockDim.x + threadIdx.x) >> 6;
    const int nwaves = (gridDim.x * blockDim.x) >> 6;
    const int col    = lane * 8;               // 64 lanes x 8 elems = 512 = C

    // Hoist W fragments (tiny, L1/L2-resident): W is [2][1024] row-major.
    float w0g[8], w0v[8], w1g[8], w1v[8];
    load8f(W + 0*1024 +       col, w0g);
    load8f(W + 0*1024 + 512 + col, w0v);
    load8f(W + 1*1024 +       col, w1g);
    load8f(W + 1*1024 + 512 + col, w1v);
    const float b0 = b[0];
    const float b1 = b[1];

    for (int row = wid; row < nrows; row += nwaves) {
        float gf[8], vf[8];
        load8f(g + (size_t)row * 512 + col, gf);
        load8f(v + (size_t)row * 512 + col, vf);

        float s0 = 0.f, s1 = 0.f;
#pragma unroll
        for (int k = 0; k < 8; ++k) {
            s0 = fmaf(gf[k], w0g[k], s0);
            s0 = fmaf(vf[k], w0v[k], s0);
            s1 = fmaf(gf[k], w1g[k], s1);
            s1 = fmaf(vf[k], w1v[k], s1);
        }
        // 64-lane butterfly reduction (all lanes end with the full sums)
#pragma unroll
        for (int m = 1; m < 64; m <<= 1) {
            s0 += __shfl_xor(s0, m, 64);
            s1 += __shfl_xor(s1, m, 64);
        }
        const float l0 = s0 + b0;
        const float l1 = s1 + b1;
        // 2-way softmax: a0 = 1/(1+e^(l1-l0)); robust at extremes (e->inf => a0->0).
        const float e  = __expf(l1 - l0);
        const float a0 = 1.0f / (1.0f + e);
        const float a1 = 1.0f - a0;

        float og[8], ov[8];
#pragma unroll
        for (int k = 0; k < 8; ++k) {
            og[k] = a0 * gf[k];
            ov[k] = a1 * vf[k];
        }
        float* orow = out + (size_t)row * 1024;
        store8f(orow +       col, og);
        store8f(orow + 512 + col, ov);
    }
}

extern "C" void kernel_launch(void* const* d_in, const int* in_sizes, int n_in,
                              void* d_out, int out_size, void* d_ws, size_t ws_size,
                              hipStream_t stream) {
    const float* g = (const float*)d_in[0];
    const float* v = (const float*)d_in[1];
    const float* W = (const float*)d_in[2];
    const float* b = (const float*)d_in[3];
    float* out = (float*)d_out;

    const int nrows = in_sizes[0] / 512;       // 65536
    const int blocks = 2048;                   // 8192 waves, 8 rows/wave
    hipLaunchKernelGGL(attentive_fusion_kernel, dim3(blocks), dim3(256), 0, stream,
                       g, v, W, b, out, nrows);
}

// Round 6
// 106.577 us; speedup vs baseline: 1.0432x; 1.0432x over previous
//
#include <hip/hip_runtime.h>

// B=65536 rows, C=512. All device buffers FLOAT32.
//   g_f [B,C], v_f [B,C], W [2,2C], b [2]  ->  out [B,2C] f32.
// out = [a0*g | a1*v], att = softmax([g|v] @ W^T + b, axis=1).
// Traffic: 268 MB read + 268 MB write = 536 MB -> ~85 us floor @ 6.3 TB/s.
//
// R5: 111 us (4.8 TB/s) with 32B-stride per-lane layout (each dwordx4 at 50%
// line density -> 2x TA/L1 requests per byte). R6: segment-partitioned layout,
// every load/store instruction is 64 lanes x 16B fully contiguous (1 KB).

__device__ __forceinline__ float4 ld4(const float* p) {
    return *reinterpret_cast<const float4*>(p);
}
__device__ __forceinline__ void st4(float* p, float4 x) {
    *reinterpret_cast<float4*>(p) = x;
}
__device__ __forceinline__ float dot4(float4 x, float4 w, float acc) {
    acc = fmaf(x.x, w.x, acc); acc = fmaf(x.y, w.y, acc);
    acc = fmaf(x.z, w.z, acc); acc = fmaf(x.w, w.w, acc);
    return acc;
}
__device__ __forceinline__ float4 scale4(float s, float4 x) {
    float4 r; r.x = s*x.x; r.y = s*x.y; r.z = s*x.z; r.w = s*x.w; return r;
}

__global__ __launch_bounds__(256) void attentive_fusion_kernel(
    const float* __restrict__ g, const float* __restrict__ v,
    const float* __restrict__ W, const float* __restrict__ b,
    float* __restrict__ out, int nrows)
{
    const int lane   = threadIdx.x & 63;
    const int wid    = (blockIdx.x * blockDim.x + threadIdx.x) >> 6;
    const int nwaves = (gridDim.x * blockDim.x) >> 6;
    const int c4     = lane * 4;           // 64 lanes x 4 floats = 256/segment

    // W [2][1024]: per-lane fragments under the segment mapping (L1-resident).
    const float4 w0a = ld4(W +    0 + c4);   // W0 . g seg0 (cols   0..255)
    const float4 w0b = ld4(W +  256 + c4);   // W0 . g seg1 (cols 256..511)
    const float4 w0c = ld4(W +  512 + c4);   // W0 . v seg0
    const float4 w0d = ld4(W +  768 + c4);   // W0 . v seg1
    const float4 w1a = ld4(W + 1024 + c4);
    const float4 w1b = ld4(W + 1280 + c4);
    const float4 w1c = ld4(W + 1536 + c4);
    const float4 w1d = ld4(W + 1792 + c4);
    const float b0 = b[0];
    const float b1 = b[1];

    for (int row = wid; row < nrows; row += nwaves) {
        const float* gr = g + (size_t)row * 512;
        const float* vr = v + (size_t)row * 512;
        // each instruction: 64 lanes x 16B contiguous (1 KB)
        const float4 ga = ld4(gr +       c4);
        const float4 gb = ld4(gr + 256 + c4);
        const float4 va = ld4(vr +       c4);
        const float4 vb = ld4(vr + 256 + c4);

        float s0 = 0.f, s1 = 0.f;
        s0 = dot4(ga, w0a, s0); s0 = dot4(gb, w0b, s0);
        s0 = dot4(va, w0c, s0); s0 = dot4(vb, w0d, s0);
        s1 = dot4(ga, w1a, s1); s1 = dot4(gb, w1b, s1);
        s1 = dot4(va, w1c, s1); s1 = dot4(vb, w1d, s1);

        // 8-shfl dual reduction: fold lane^32, butterfly one half-selected
        // value over 32 lanes, then exchange halves.
        s0 += __shfl_xor(s0, 32, 64);
        s1 += __shfl_xor(s1, 32, 64);
        float u = (lane & 32) ? s1 : s0;
#pragma unroll
        for (int m = 1; m < 32; m <<= 1)
            u += __shfl_xor(u, m, 64);
        const float other = __shfl_xor(u, 32, 64);
        const float l0 = ((lane & 32) ? other : u) + b0;
        const float l1 = ((lane & 32) ? u : other) + b1;

        // 2-way softmax: a0 = 1/(1+e^(l1-l0)); robust at extremes.
        const float e  = __expf(l1 - l0);
        const float a0 = 1.0f / (1.0f + e);
        const float a1 = 1.0f - a0;

        float* orow = out + (size_t)row * 1024;
        st4(orow +       c4, scale4(a0, ga));
        st4(orow + 256 + c4, scale4(a0, gb));
        st4(orow + 512 + c4, scale4(a1, va));
        st4(orow + 768 + c4, scale4(a1, vb));
    }
}

extern "C" void kernel_launch(void* const* d_in, const int* in_sizes, int n_in,
                              void* d_out, int out_size, void* d_ws, size_t ws_size,
                              hipStream_t stream) {
    const float* g = (const float*)d_in[0];
    const float* v = (const float*)d_in[1];
    const float* W = (const float*)d_in[2];
    const float* b = (const float*)d_in[3];
    float* out = (float*)d_out;

    const int nrows = in_sizes[0] / 512;       // 65536
    const int blocks = 2048;                   // 8192 waves, 8 rows/wave
    hipLaunchKernelGGL(attentive_fusion_kernel, dim3(blocks), dim3(256), 0, stream,
                       g, v, W, b, out, nrows);
}

// Round 7
// 104.583 us; speedup vs baseline: 1.0631x; 1.0191x over previous
//
#include <hip/hip_runtime.h>

// B=65536 rows, C=512. All device buffers FLOAT32.
//   g_f [B,C], v_f [B,C], W [2,2C], b [2]  ->  out [B,2C] f32.
// out = [a0*g | a1*v], att = softmax([g|v] @ W^T + b, axis=1).
// Traffic: 268 MB read + 268 MB write = 536 MB -> 85.2 us floor @ 6.29 TB/s.
//
// R5: 111.2 us (strided per-lane layout). R6: 106.6 us (1KB-coalesced
// instructions). R7: chunked row ownership — wave wid owns rows
// [8*wid, 8*wid+8) so each wave streams 16KB/16KB/32KB contiguous chunks
// (copy-bench-like DRAM page locality) instead of 32MB jumps per iteration.

#define ROWS_PER_WAVE 8

__device__ __forceinline__ float4 ld4(const float* p) {
    return *reinterpret_cast<const float4*>(p);
}
__device__ __forceinline__ void st4(float* p, float4 x) {
    *reinterpret_cast<float4*>(p) = x;
}
__device__ __forceinline__ float dot4(float4 x, float4 w, float acc) {
    acc = fmaf(x.x, w.x, acc); acc = fmaf(x.y, w.y, acc);
    acc = fmaf(x.z, w.z, acc); acc = fmaf(x.w, w.w, acc);
    return acc;
}
__device__ __forceinline__ float4 scale4(float s, float4 x) {
    float4 r; r.x = s*x.x; r.y = s*x.y; r.z = s*x.z; r.w = s*x.w; return r;
}

__global__ __launch_bounds__(256) void attentive_fusion_kernel(
    const float* __restrict__ g, const float* __restrict__ v,
    const float* __restrict__ W, const float* __restrict__ b,
    float* __restrict__ out, int nrows)
{
    const int lane = threadIdx.x & 63;
    const int wid  = (blockIdx.x * blockDim.x + threadIdx.x) >> 6;
    const int c4   = lane * 4;             // 64 lanes x 4 floats = 256/segment

    // W [2][1024]: per-lane fragments under the segment mapping (L2-resident).
    const float4 w0a = ld4(W +    0 + c4);   // W0 . g seg0 (cols   0..255)
    const float4 w0b = ld4(W +  256 + c4);   // W0 . g seg1 (cols 256..511)
    const float4 w0c = ld4(W +  512 + c4);   // W0 . v seg0
    const float4 w0d = ld4(W +  768 + c4);   // W0 . v seg1
    const float4 w1a = ld4(W + 1024 + c4);
    const float4 w1b = ld4(W + 1280 + c4);
    const float4 w1c = ld4(W + 1536 + c4);
    const float4 w1d = ld4(W + 1792 + c4);
    const float b0 = b[0];
    const float b1 = b[1];

    const int row0 = wid * ROWS_PER_WAVE;
#pragma unroll 2
    for (int r = 0; r < ROWS_PER_WAVE; ++r) {
        const int row = row0 + r;
        if (row >= nrows) break;
        const float* gr = g + (size_t)row * 512;
        const float* vr = v + (size_t)row * 512;
        // each instruction: 64 lanes x 16B contiguous (1 KB)
        const float4 ga = ld4(gr +       c4);
        const float4 gb = ld4(gr + 256 + c4);
        const float4 va = ld4(vr +       c4);
        const float4 vb = ld4(vr + 256 + c4);

        float s0 = 0.f, s1 = 0.f;
        s0 = dot4(ga, w0a, s0); s0 = dot4(gb, w0b, s0);
        s0 = dot4(va, w0c, s0); s0 = dot4(vb, w0d, s0);
        s1 = dot4(ga, w1a, s1); s1 = dot4(gb, w1b, s1);
        s1 = dot4(va, w1c, s1); s1 = dot4(vb, w1d, s1);

        // 8-shfl dual reduction: fold lane^32, butterfly one half-selected
        // value over 32 lanes, then exchange halves.
        s0 += __shfl_xor(s0, 32, 64);
        s1 += __shfl_xor(s1, 32, 64);
        float u = (lane & 32) ? s1 : s0;
#pragma unroll
        for (int m = 1; m < 32; m <<= 1)
            u += __shfl_xor(u, m, 64);
        const float other = __shfl_xor(u, 32, 64);
        const float l0 = ((lane & 32) ? other : u) + b0;
        const float l1 = ((lane & 32) ? u : other) + b1;

        // 2-way softmax: a0 = 1/(1+e^(l1-l0)); robust at extremes.
        const float e  = __expf(l1 - l0);
        const float a0 = 1.0f / (1.0f + e);
        const float a1 = 1.0f - a0;

        float* orow = out + (size_t)row * 1024;
        st4(orow +       c4, scale4(a0, ga));
        st4(orow + 256 + c4, scale4(a0, gb));
        st4(orow + 512 + c4, scale4(a1, va));
        st4(orow + 768 + c4, scale4(a1, vb));
    }
}

extern "C" void kernel_launch(void* const* d_in, const int* in_sizes, int n_in,
                              void* d_out, int out_size, void* d_ws, size_t ws_size,
                              hipStream_t stream) {
    const float* g = (const float*)d_in[0];
    const float* v = (const float*)d_in[1];
    const float* W = (const float*)d_in[2];
    const float* b = (const float*)d_in[3];
    float* out = (float*)d_out;

    const int nrows = in_sizes[0] / 512;                 // 65536
    const int waves_needed = (nrows + ROWS_PER_WAVE - 1) / ROWS_PER_WAVE;
    const int blocks = (waves_needed + 3) / 4;           // 4 waves per block -> 2048
    hipLaunchKernelGGL(attentive_fusion_kernel, dim3(blocks), dim3(256), 0, stream,
                       g, v, W, b, out, nrows);
}

// Round 9
// 97.257 us; speedup vs baseline: 1.1432x; 1.0753x over previous
//
#include <hip/hip_runtime.h>

// B=65536 rows, C=512. All device buffers FLOAT32.
//   g_f [B,C], v_f [B,C], W [2,2C], b [2]  ->  out [B,2C] f32.
// out = [a0*g | a1*v], att = softmax([g|v] @ W^T + b, axis=1).
// Traffic: 268 MB read + 268 MB write = 536 MB -> 85.2 us floor @ 6.29 TB/s.
//
// R5 111.2us (strided lanes) -> R6 106.6 (1KB-coalesced) -> R7 104.6 (chunked
// rows). R8: explicit next-row load prefetch (double-buffer), nontemporal
// loads/stores (streaming data, zero reuse; W stays cached), branch-free
// 8-row fast path. NOTE: nontemporal builtins need native clang vector types
// (ext_vector_type), not HIP_vector_type — hence f4 below.

#define ROWS_PER_WAVE 8

typedef float f4 __attribute__((ext_vector_type(4)));

__device__ __forceinline__ f4 ldnt(const float* p) {
    return __builtin_nontemporal_load(reinterpret_cast<const f4*>(p));
}
__device__ __forceinline__ void stnt(float* p, f4 x) {
    __builtin_nontemporal_store(x, reinterpret_cast<f4*>(p));
}
__device__ __forceinline__ f4 ld4(const float* p) {
    return *reinterpret_cast<const f4*>(p);
}
__device__ __forceinline__ float dot4(f4 x, f4 w, float acc) {
    acc = fmaf(x.x, w.x, acc); acc = fmaf(x.y, w.y, acc);
    acc = fmaf(x.z, w.z, acc); acc = fmaf(x.w, w.w, acc);
    return acc;
}

__global__ __launch_bounds__(256) void attentive_fusion_kernel(
    const float* __restrict__ g, const float* __restrict__ v,
    const float* __restrict__ W, const float* __restrict__ b,
    float* __restrict__ out, int nrows)
{
    const int lane = threadIdx.x & 63;
    const int wid  = (blockIdx.x * blockDim.x + threadIdx.x) >> 6;
    const int c4   = lane * 4;             // 64 lanes x 4 floats = 256/segment

    // W [2][1024]: per-lane fragments under the segment mapping (cached).
    const f4 w0a = ld4(W +    0 + c4);
    const f4 w0b = ld4(W +  256 + c4);
    const f4 w0c = ld4(W +  512 + c4);
    const f4 w0d = ld4(W +  768 + c4);
    const f4 w1a = ld4(W + 1024 + c4);
    const f4 w1b = ld4(W + 1280 + c4);
    const f4 w1c = ld4(W + 1536 + c4);
    const f4 w1d = ld4(W + 1792 + c4);
    const float b0 = b[0];
    const float b1 = b[1];

    const int row0 = wid * ROWS_PER_WAVE;
    if (row0 + ROWS_PER_WAVE <= nrows) {
        // fast path: branch-free, software-pipelined over 8 contiguous rows
        const float* gr   = g   + (size_t)row0 * 512  + c4;
        const float* vr   = v   + (size_t)row0 * 512  + c4;
        float*       orow = out + (size_t)row0 * 1024 + c4;

        f4 ga = ldnt(gr), gb = ldnt(gr + 256);
        f4 va = ldnt(vr), vb = ldnt(vr + 256);

#pragma unroll
        for (int r = 0; r < ROWS_PER_WAVE; ++r) {
            f4 nga, ngb, nva, nvb;
            if (r + 1 < ROWS_PER_WAVE) {   // issue next row's loads FIRST
                const float* gn = gr + (size_t)(r + 1) * 512;
                const float* vn = vr + (size_t)(r + 1) * 512;
                nga = ldnt(gn); ngb = ldnt(gn + 256);
                nva = ldnt(vn); nvb = ldnt(vn + 256);
            }

            float s0 = 0.f, s1 = 0.f;
            s0 = dot4(ga, w0a, s0); s0 = dot4(gb, w0b, s0);
            s0 = dot4(va, w0c, s0); s0 = dot4(vb, w0d, s0);
            s1 = dot4(ga, w1a, s1); s1 = dot4(gb, w1b, s1);
            s1 = dot4(va, w1c, s1); s1 = dot4(vb, w1d, s1);

            // 8-shfl dual reduction
            s0 += __shfl_xor(s0, 32, 64);
            s1 += __shfl_xor(s1, 32, 64);
            float u = (lane & 32) ? s1 : s0;
#pragma unroll
            for (int m = 1; m < 32; m <<= 1)
                u += __shfl_xor(u, m, 64);
            const float other = __shfl_xor(u, 32, 64);
            const float l0 = ((lane & 32) ? other : u) + b0;
            const float l1 = ((lane & 32) ? u : other) + b1;

            const float e  = __expf(l1 - l0);
            const float a0 = 1.0f / (1.0f + e);
            const float a1 = 1.0f - a0;

            float* po = orow + (size_t)r * 1024;
            stnt(po,       a0 * ga);
            stnt(po + 256, a0 * gb);
            stnt(po + 512, a1 * va);
            stnt(po + 768, a1 * vb);

            ga = nga; gb = ngb; va = nva; vb = nvb;
        }
    } else {
        // tail path (not taken for B=65536, kept for generality)
        for (int row = row0; row < nrows; ++row) {
            const float* gr = g + (size_t)row * 512;
            const float* vr = v + (size_t)row * 512;
            f4 ga = ld4(gr + c4),       gb = ld4(gr + 256 + c4);
            f4 va = ld4(vr + c4),       vb = ld4(vr + 256 + c4);
            float s0 = 0.f, s1 = 0.f;
            s0 = dot4(ga, w0a, s0); s0 = dot4(gb, w0b, s0);
            s0 = dot4(va, w0c, s0); s0 = dot4(vb, w0d, s0);
            s1 = dot4(ga, w1a, s1); s1 = dot4(gb, w1b, s1);
            s1 = dot4(va, w1c, s1); s1 = dot4(vb, w1d, s1);
            s0 += __shfl_xor(s0, 32, 64);
            s1 += __shfl_xor(s1, 32, 64);
            float u = (lane & 32) ? s1 : s0;
            for (int m = 1; m < 32; m <<= 1) u += __shfl_xor(u, m, 64);
            const float other = __shfl_xor(u, 32, 64);
            const float l0 = ((lane & 32) ? other : u) + b0;
            const float l1 = ((lane & 32) ? u : other) + b1;
            const float e  = __expf(l1 - l0);
            const float a0 = 1.0f / (1.0f + e);
            const float a1 = 1.0f - a0;
            float* po = out + (size_t)row * 1024;
            *reinterpret_cast<f4*>(po +       c4) = a0 * ga;
            *reinterpret_cast<f4*>(po + 256 + c4) = a0 * gb;
            *reinterpret_cast<f4*>(po + 512 + c4) = a1 * va;
            *reinterpret_cast<f4*>(po + 768 + c4) = a1 * vb;
        }
    }
}

extern "C" void kernel_launch(void* const* d_in, const int* in_sizes, int n_in,
                              void* d_out, int out_size, void* d_ws, size_t ws_size,
                              hipStream_t stream) {
    const float* g = (const float*)d_in[0];
    const float* v = (const float*)d_in[1];
    const float* W = (const float*)d_in[2];
    const float* b = (const float*)d_in[3];
    float* out = (float*)d_out;

    const int nrows = in_sizes[0] / 512;                 // 65536
    const int waves_needed = (nrows + ROWS_PER_WAVE - 1) / ROWS_PER_WAVE;
    const int blocks = (waves_needed + 3) / 4;           // 4 waves/block -> 2048
    hipLaunchKernelGGL(attentive_fusion_kernel, dim3(blocks), dim3(256), 0, stream,
                       g, v, W, b, out, nrows);
}

// Round 12
// 96.830 us; speedup vs baseline: 1.1483x; 1.0044x over previous
//
#include <hip/hip_runtime.h>

// B=65536 rows, C=512. All device buffers FLOAT32.
//   g_f [B,C], v_f [B,C], W [2,2C], b [2]  ->  out [B,2C] f32.
// out = [a0*g | a1*v], att = softmax([g|v] @ W^T + b, axis=1).
// Traffic: 268 MB read + 268 MB write = 536 MB -> 85.2 us floor @ 6.29 TB/s.
//
// R5 111.2us (strided lanes) -> R6 106.6 (1KB-coalesced) -> R7 104.6 (chunked
// rows) -> R9 97.3 (prefetch + NT + branch-free). R10/11: replace the 8x
// ds_bpermute shfl butterfly (~300cy serial/row, LDS pipe) with the canonical
// GCN DPP reduction (row_shr 1/2/4/8 + row_bcast 15/31, ~30cy, VALU pipe) +
// readlane(63) SGPR broadcast. DPP ctrl must be an immediate -> template arg.

#define ROWS_PER_WAVE 8

typedef float f4 __attribute__((ext_vector_type(4)));

__device__ __forceinline__ f4 ldnt(const float* p) {
    return __builtin_nontemporal_load(reinterpret_cast<const f4*>(p));
}
__device__ __forceinline__ void stnt(float* p, f4 x) {
    __builtin_nontemporal_store(x, reinterpret_cast<f4*>(p));
}
__device__ __forceinline__ f4 ld4(const float* p) {
    return *reinterpret_cast<const f4*>(p);
}
__device__ __forceinline__ float dot4(f4 x, f4 w, float acc) {
    acc = fmaf(x.x, w.x, acc); acc = fmaf(x.y, w.y, acc);
    acc = fmaf(x.z, w.z, acc); acc = fmaf(x.w, w.w, acc);
    return acc;
}

// one DPP-shifted add: x + dpp_mov(x, CTRL), 0-fill out-of-bounds lanes.
// CTRL as template param: builtin requires a constant-integer immediate.
template <int CTRL>
__device__ __forceinline__ float dpp_add(float x) {
    int y = __builtin_amdgcn_update_dpp(0, __float_as_int(x), CTRL,
                                        0xf, 0xf, true);
    return x + __int_as_float(y);
}

// full 64-lane sum, result uniform (canonical GCN cross-lane reduction:
// after row_shr 1/2/4/8 lane{15,31,47,63} hold per-row16 sums; bcast15
// folds into lane31 (sum 0..31), bcast31 folds low half into lane63).
__device__ __forceinline__ float wave_sum_bcast(float x) {
    x = dpp_add<0x111>(x);   // row_shr:1
    x = dpp_add<0x112>(x);   // row_shr:2
    x = dpp_add<0x114>(x);   // row_shr:4
    x = dpp_add<0x118>(x);   // row_shr:8
    x = dpp_add<0x142>(x);   // row_bcast:15
    x = dpp_add<0x143>(x);   // row_bcast:31
    return __int_as_float(__builtin_amdgcn_readlane(__float_as_int(x), 63));
}

__global__ __launch_bounds__(256) void attentive_fusion_kernel(
    const float* __restrict__ g, const float* __restrict__ v,
    const float* __restrict__ W, const float* __restrict__ b,
    float* __restrict__ out, int nrows)
{
    const int lane = threadIdx.x & 63;
    const int wid  = (blockIdx.x * blockDim.x + threadIdx.x) >> 6;
    const int c4   = lane * 4;             // 64 lanes x 4 floats = 256/segment

    // W [2][1024]: per-lane fragments under the segment mapping (cached).
    const f4 w0a = ld4(W +    0 + c4);
    const f4 w0b = ld4(W +  256 + c4);
    const f4 w0c = ld4(W +  512 + c4);
    const f4 w0d = ld4(W +  768 + c4);
    const f4 w1a = ld4(W + 1024 + c4);
    const f4 w1b = ld4(W + 1280 + c4);
    const f4 w1c = ld4(W + 1536 + c4);
    const f4 w1d = ld4(W + 1792 + c4);
    const float b0 = b[0];
    const float b1 = b[1];

    const int row0 = wid * ROWS_PER_WAVE;
    if (row0 + ROWS_PER_WAVE <= nrows) {
        // fast path: branch-free, software-pipelined over 8 contiguous rows
        const float* gr   = g   + (size_t)row0 * 512  + c4;
        const float* vr   = v   + (size_t)row0 * 512  + c4;
        float*       orow = out + (size_t)row0 * 1024 + c4;

        f4 ga = ldnt(gr), gb = ldnt(gr + 256);
        f4 va = ldnt(vr), vb = ldnt(vr + 256);

#pragma unroll
        for (int r = 0; r < ROWS_PER_WAVE; ++r) {
            f4 nga, ngb, nva, nvb;
            if (r + 1 < ROWS_PER_WAVE) {   // issue next row's loads FIRST
                const float* gn = gr + (size_t)(r + 1) * 512;
                const float* vn = vr + (size_t)(r + 1) * 512;
                nga = ldnt(gn); ngb = ldnt(gn + 256);
                nva = ldnt(vn); nvb = ldnt(vn + 256);
            }

            float s0 = 0.f, s1 = 0.f;
            s0 = dot4(ga, w0a, s0); s0 = dot4(gb, w0b, s0);
            s0 = dot4(va, w0c, s0); s0 = dot4(vb, w0d, s0);
            s1 = dot4(ga, w1a, s1); s1 = dot4(gb, w1b, s1);
            s1 = dot4(va, w1c, s1); s1 = dot4(vb, w1d, s1);

            // two independent DPP reduction chains (VALU pipe, ~30cy each)
            const float l0 = wave_sum_bcast(s0) + b0;
            const float l1 = wave_sum_bcast(s1) + b1;

            const float e  = __expf(l1 - l0);
            const float a0 = 1.0f / (1.0f + e);
            const float a1 = 1.0f - a0;

            float* po = orow + (size_t)r * 1024;
            stnt(po,       a0 * ga);
            stnt(po + 256, a0 * gb);
            stnt(po + 512, a1 * va);
            stnt(po + 768, a1 * vb);

            ga = nga; gb = ngb; va = nva; vb = nvb;
        }
    } else {
        // tail path (not taken for B=65536, kept for generality)
        for (int row = row0; row < nrows; ++row) {
            const float* gr = g + (size_t)row * 512;
            const float* vr = v + (size_t)row * 512;
            f4 ga = ld4(gr + c4),       gb = ld4(gr + 256 + c4);
            f4 va = ld4(vr + c4),       vb = ld4(vr + 256 + c4);
            float s0 = 0.f, s1 = 0.f;
            s0 = dot4(ga, w0a, s0); s0 = dot4(gb, w0b, s0);
            s0 = dot4(va, w0c, s0); s0 = dot4(vb, w0d, s0);
            s1 = dot4(ga, w1a, s1); s1 = dot4(gb, w1b, s1);
            s1 = dot4(va, w1c, s1); s1 = dot4(vb, w1d, s1);
            const float l0 = wave_sum_bcast(s0) + b0;
            const float l1 = wave_sum_bcast(s1) + b1;
            const float e  = __expf(l1 - l0);
            const float a0 = 1.0f / (1.0f + e);
            const float a1 = 1.0f - a0;
            float* po = out + (size_t)row * 1024;
            *reinterpret_cast<f4*>(po +       c4) = a0 * ga;
            *reinterpret_cast<f4*>(po + 256 + c4) = a0 * gb;
            *reinterpret_cast<f4*>(po + 512 + c4) = a1 * va;
            *reinterpret_cast<f4*>(po + 768 + c4) = a1 * vb;
        }
    }
}

extern "C" void kernel_launch(void* const* d_in, const int* in_sizes, int n_in,
                              void* d_out, int out_size, void* d_ws, size_t ws_size,
                              hipStream_t stream) {
    const float* g = (const float*)d_in[0];
    const float* v = (const float*)d_in[1];
    const float* W = (const float*)d_in[2];
    const float* b = (const float*)d_in[3];
    float* out = (float*)d_out;

    const int nrows = in_sizes[0] / 512;                 // 65536
    const int waves_needed = (nrows + ROWS_PER_WAVE - 1) / ROWS_PER_WAVE;
    const int blocks = (waves_needed + 3) / 4;           // 4 waves/block -> 2048
    hipLaunchKernelGGL(attentive_fusion_kernel, dim3(blocks), dim3(256), 0, stream,
                       g, v, W, b, out, nrows);
}